// Round 21
// baseline (119.412 us; speedup 1.0000x reference)
//
#include <hip/hip_runtime.h>
#include <cstdint>
#include <cstddef>

typedef unsigned short u16;
typedef unsigned int u32;
typedef __bf16 bf16x8 __attribute__((ext_vector_type(8)));
typedef float f32x4 __attribute__((ext_vector_type(4)));
typedef u32 u32x2 __attribute__((ext_vector_type(2)));
typedef u32 u32x4 __attribute__((ext_vector_type(4)));
typedef unsigned short u16x8 __attribute__((ext_vector_type(8)));
typedef short s16x4 __attribute__((ext_vector_type(4)));

// f32 -> bf16 round-to-nearest-even (finite inputs only)
__device__ __forceinline__ u16 f2bf(float f) {
    u32 u = __float_as_uint(f);
    u += 0x7fffu + ((u >> 16) & 1u);
    return (u16)(u >> 16);
}

// raw exp2: single v_exp_f32 (denormals flush to 0 = correct softmax tail)
__device__ __forceinline__ float fexp2(float x) {
    float r;
    asm("v_exp_f32 %0, %1" : "=v"(r) : "v"(x));
    return r;
}

// async global->LDS, 16B per lane. LDS ptr must be wave-uniform; HW adds lane*16.
__device__ __forceinline__ void gl16(const void* g, void* l) {
    __builtin_amdgcn_global_load_lds(
        (const __attribute__((address_space(1))) unsigned int*)g,
        (__attribute__((address_space(3))) unsigned int*)l, 16, 0, 0);
}

// ---------------------------------------------------------------- conversions
// z 0..3: W [1024][1024] f32 (k,n) -> bf16 (n,k). z 4..11: x f32 -> bf16 chunks.
__global__ __launch_bounds__(256) void cvt_all_k(const float* __restrict__ Wq,
                                                 const float* __restrict__ Wk,
                                                 const float* __restrict__ Wv,
                                                 const float* __restrict__ Wo,
                                                 const float* __restrict__ x,
                                                 u16* __restrict__ oqkv,
                                                 u16* __restrict__ oo,
                                                 u16* __restrict__ ox) {
    const int z = blockIdx.z;
    const int bx = blockIdx.x, by = blockIdx.y;
    const int t = threadIdx.x;
    if (z >= 4) {   // x conversion: 8 f32 per thread
        int i = ((z - 4) * 256 + by * 16 + bx) * 256 + t;
        const float4* xv = (const float4*)x;
        float4 a = xv[2 * i], b = xv[2 * i + 1];
        ushort4 r0, r1;
        r0.x = f2bf(a.x); r0.y = f2bf(a.y); r0.z = f2bf(a.z); r0.w = f2bf(a.w);
        r1.x = f2bf(b.x); r1.y = f2bf(b.y); r1.z = f2bf(b.z); r1.w = f2bf(b.w);
        ((ushort4*)ox)[2 * i] = r0;
        ((ushort4*)ox)[2 * i + 1] = r1;
        return;
    }
    __shared__ float tile[64][65];
    const float* W = (z == 0) ? Wq : (z == 1) ? Wk : (z == 2) ? Wv : Wo;
    u16* o = (z < 3) ? (oqkv + ((size_t)z << 20)) : oo;
    const int tn = t & 63, tr = t >> 6;
#pragma unroll
    for (int r = 0; r < 16; ++r) {
        int kk = r * 4 + tr;
        tile[kk][tn] = W[(size_t)(by * 64 + kk) * 1024 + bx * 64 + tn];
    }
    __syncthreads();
#pragma unroll
    for (int r = 0; r < 16; ++r) {
        int nn = r * 4 + tr;
        o[(size_t)(bx * 64 + nn) * 1024 + by * 64 + tn] = f2bf(tile[tn][nn]);
    }
}

// ---------------------------------------------------------------- GEMM 128x128
// 2-buffer (32KB) drain pipeline: stage(t+1) -> compute(t) -> vmcnt(0)+barrier.
// Rationale: the 3-buffer/48KB variant pinned occupancy at 2 blocks/CU; 32KB
// admits all 3 grid blocks per CU (m97/m114: cross-block TLP hides the drain
// stall better than source-level pipelining). Zero-conflict both-sides swizzle.
// MODE 0: fused QKV epilogue; V-blocks store via LDS transpose (needs 34.8KB
// scratch -> sh sized 17408 u16). MODE 1: f32 out + bias.
template <int MODE>
__global__ __launch_bounds__(256) void gemm_k(
    const u16* __restrict__ A, const u16* __restrict__ Bt,
    const float* __restrict__ bias0, const float* __restrict__ bias1,
    const float* __restrict__ bias2,
    u16* __restrict__ oq, u16* __restrict__ ok_, u16* __restrict__ ov,
    float* __restrict__ oc) {
    __shared__ __align__(16) u16 sh[17408];   // A dbuf 16KB | B dbuf 16KB; epi 34.8KB
    const int t = threadIdx.x, w = t >> 6, lane = t & 63;
    const int lr = lane & 15, lg = lane >> 4;
    const int brow = blockIdx.x * 128, bcol = blockIdx.y * 128;
    const int wr = w >> 1, wc = w & 1;
    const char* Ab = (const char*)A + (size_t)brow * 2048;
    const char* Bb = (const char*)Bt + (size_t)bcol * 2048;
    const int lrow = lane >> 2;
    const int lcol = (((lane & 3) ^ ((lane >> 3) & 3)) << 4);
    const int r0a = w * 32, r0b = w * 32 + 16;
    const size_t ga = (size_t)(r0a + lrow) * 2048 + lcol;
    const size_t gb = (size_t)(r0b + lrow) * 2048 + lcol;
    const int rsw = ((lg ^ ((lr >> 1) & 3)) << 4);

    f32x4 acc[4][4];
#pragma unroll
    for (int m = 0; m < 4; ++m)
#pragma unroll
        for (int n = 0; n < 4; ++n) acc[m][n] = (f32x4){0.f, 0.f, 0.f, 0.f};

    // prologue: stage K-step 0 into buffer 0
    gl16(Ab + ga, (char*)sh + r0a * 64);
    gl16(Ab + gb, (char*)sh + r0b * 64);
    gl16(Bb + ga, (char*)sh + 16384 + r0a * 64);
    gl16(Bb + gb, (char*)sh + 16384 + r0b * 64);
    asm volatile("s_waitcnt vmcnt(0)" ::: "memory");
    __builtin_amdgcn_s_barrier();
    __builtin_amdgcn_sched_barrier(0);

    for (int tt = 0; tt < 32; ++tt) {
        if (tt < 31) {   // stage next K-step into the other buffer
            const int nb = (tt + 1) & 1;
            const size_t ko = (size_t)(tt + 1) * 64;   // 32 elems * 2B
            gl16(Ab + ga + ko, (char*)sh + nb * 8192 + r0a * 64);
            gl16(Ab + gb + ko, (char*)sh + nb * 8192 + r0b * 64);
            gl16(Bb + ga + ko, (char*)sh + 16384 + nb * 8192 + r0a * 64);
            gl16(Bb + gb + ko, (char*)sh + 16384 + nb * 8192 + r0b * 64);
        }
        const char* AsB = (const char*)sh + (tt & 1) * 8192;
        const char* BsB = (const char*)sh + 16384 + (tt & 1) * 8192;
        bf16x8 af[4], bfr[4];
#pragma unroll
        for (int m = 0; m < 4; ++m)
            af[m] = *(const bf16x8*)(AsB + (wr * 64 + m * 16 + lr) * 64 + rsw);
#pragma unroll
        for (int n = 0; n < 4; ++n)
            bfr[n] = *(const bf16x8*)(BsB + (wc * 64 + n * 16 + lr) * 64 + rsw);
#pragma unroll
        for (int m = 0; m < 4; ++m)
#pragma unroll
            for (int n = 0; n < 4; ++n)
                acc[m][n] = __builtin_amdgcn_mfma_f32_16x16x32_bf16(af[m], bfr[n],
                                                                    acc[m][n], 0, 0, 0);
        // drain next-tile staging (hidden by co-resident blocks' waves)
        asm volatile("s_waitcnt vmcnt(0)" ::: "memory");
        __builtin_amdgcn_s_barrier();
        __builtin_amdgcn_sched_barrier(0);
    }

    const float QSCALE = 0.125f * 1.44269504f;
    if (MODE == 0 && bcol >= 2048) {
        // V block: transpose via LDS, store coalesced 128B runs into vt.
        const int b = brow >> 11, l0 = brow & 2047;
        __syncthreads();
#pragma unroll
        for (int n = 0; n < 4; ++n) {
            const int cl = wc * 64 + n * 16 + lr;
            const float bb2 = bias2[bcol - 2048 + cl];
#pragma unroll
            for (int m = 0; m < 4; ++m)
#pragma unroll
                for (int r = 0; r < 4; ++r) {
                    int ll = wr * 64 + m * 16 + 4 * lg + r;
                    sh[cl * 136 + ll] = f2bf(acc[m][n][r] + bb2);
                }
        }
        __syncthreads();
        const int rr = t >> 1, hf = t & 1;
        const u16* src = sh + rr * 136 + hf * 64;
        u16* dst = ov + ((size_t)b * 1024 + (bcol - 2048) + rr) * 2048 +
                   l0 + hf * 64;
#pragma unroll
        for (int i = 0; i < 8; ++i)
            *(u16x8*)(dst + i * 8) = *(const u16x8*)(src + i * 8);
        return;
    }
#pragma unroll
    for (int n = 0; n < 4; ++n) {
        const int col = bcol + wc * 64 + n * 16 + lr;
        if (MODE == 0) {
#pragma unroll
            for (int m = 0; m < 4; ++m)
#pragma unroll
                for (int r = 0; r < 4; ++r) {
                    int row = brow + wr * 64 + m * 16 + 4 * lg + r;
                    int b = row >> 11, l = row & 2047;
                    float val = acc[m][n][r];
                    if (col < 1024) {
                        int hh = col >> 6, d = col & 63;
                        oq[(((size_t)b * 16 + hh) * 2048 + l) * 64 + d] =
                            f2bf((val + bias0[col]) * QSCALE);
                    } else {
                        int c = col - 1024, hh = c >> 6, d = c & 63;
                        ok_[(((size_t)b * 16 + hh) * 2048 + l) * 64 + d] =
                            f2bf(val + bias1[c]);
                    }
                }
        } else {
            const float bb = bias0[col];
#pragma unroll
            for (int m = 0; m < 4; ++m)
#pragma unroll
                for (int r = 0; r < 4; ++r) {
                    int row = brow + wr * 64 + m * 16 + 4 * lg + r;
                    oc[(size_t)row * 1024 + col] = acc[m][n][r] + bb;
                }
        }
    }
}

// ---------------------------------------------------------------- attention
// (R18 version: KVBLK=128, 2-buffer depth-1, 32-row waves, max-free softmax
// in MFMA C-init, K=32 PV concatenated slice pairs, 1-deep vP/vQ V-register
// prefetch, v_exp_f32.)
__global__ __launch_bounds__(256, 2) void attn_k(const u16* __restrict__ qg_,
                                                 const u16* __restrict__ kg_,
                                                 const u16* __restrict__ vg_,
                                                 u16* __restrict__ ao) {
    __shared__ __align__(16) u16 smem[32768];   // 64KB: K0|K1 | V0|V1 (16KB ea)
    char* Kbase = (char*)smem;                  // 2 x 16384
    char* Vbase = (char*)smem + 32768;          // 2 x 16384
    const int t = threadIdx.x, w = t >> 6, lane = t & 63;
    const int lr = lane & 15, lg = lane >> 4;
    const int bid = blockIdx.y * 16 + blockIdx.x;
    const int qt = (bid >> 3) & 15;
    const int bh = ((bid >> 7) << 3) | (bid & 7);
    const int q0 = qt * 128, h = bh & 15, bb = bh >> 4;
    const float sl2 = exp2f(-0.5f * (float)(h + 1)) * 1.44269504f; // slope*log2e

    const char* khead = (const char*)(kg_ + (size_t)bh * 2048 * 64);
    const char* vhead = (const char*)(vg_ + (size_t)bh * 64 * 2048);

    const int krow = lane >> 3, ku = lane & 7;
    const int kso = (w * 32 + krow) * 128 + ((ku ^ (krow & 7)) << 4);
    const int kdo = w * 4096;
    const int vrow = lane >> 4, vgr = lane & 15;
    int vso[4];
#pragma unroll
    for (int i = 0; i < 4; ++i)
        vso[i] = (w * 16 + 4 * i + vrow) * 4096 +
                 ((vgr ^ ((4 * i + vrow) & 7)) << 4);
    const int vdo = w * 4096;

    const char* qpA = (const char*)qg_ +
                      ((size_t)bh * 2048 + q0 + w * 32 + lr) * 128;
    bf16x8 qa0A = *(const bf16x8*)(qpA + lg * 16);
    bf16x8 qa1A = *(const bf16x8*)(qpA + 64 + lg * 16);
    bf16x8 qa0B = *(const bf16x8*)(qpA + 2048 + lg * 16);
    bf16x8 qa1B = *(const bf16x8*)(qpA + 2048 + 64 + lg * 16);

    f32x4 abF2[8];
#pragma unroll
    for (int n = 0; n < 8; ++n)
#pragma unroll
        for (int r = 0; r < 4; ++r)
            abF2[n][r] = sl2 * (float)(n * 16 + 4 * lg + r - 2047) - 16.0f;
    const float ainc = sl2 * 128.0f;
    f32x4 oaccA[4], oaccB[4];
#pragma unroll
    for (int nn = 0; nn < 4; ++nn) {
        oaccA[nn] = (f32x4){0.f, 0.f, 0.f, 0.f};
        oaccB[nn] = (f32x4){0.f, 0.f, 0.f, 0.f};
    }
    f32x4 laccA = (f32x4){0.f, 0.f, 0.f, 0.f};
    f32x4 laccB = (f32x4){0.f, 0.f, 0.f, 0.f};
    const u32x4 ones32 = {0x3F803F80u, 0x3F803F80u, 0x3F803F80u, 0x3F803F80u};
    const bf16x8 onesf = __builtin_bit_cast(bf16x8, ones32);

    {
        char* kd = Kbase + kdo;
        char* vd = Vbase + vdo;
#pragma unroll
        for (int i = 0; i < 4; ++i) gl16(khead + kso + i * 1024, kd + i * 1024);
#pragma unroll
        for (int i = 0; i < 4; ++i) gl16(vhead + vso[i], vd + i * 1024);
    }
    asm volatile("s_waitcnt vmcnt(0)" ::: "memory");
    __builtin_amdgcn_s_barrier();
    __builtin_amdgcn_sched_barrier(0);

    for (int tt = 0; tt < 16; ++tt) {
        if (tt < 15) {
            const char* ks = khead + (size_t)(tt + 1) * 16384;
            const char* vs = vhead + (size_t)(tt + 1) * 256;
            char* kd = Kbase + ((tt + 1) & 1) * 16384 + kdo;
            char* vd = Vbase + ((tt + 1) & 1) * 16384 + vdo;
#pragma unroll
            for (int i = 0; i < 4; ++i) gl16(ks + kso + i * 1024, kd + i * 1024);
#pragma unroll
            for (int i = 0; i < 4; ++i) gl16(vs + vso[i], vd + i * 1024);
        }
        const char* Kc = Kbase + (tt & 1) * 16384;
        const char* Vc = Vbase + (tt & 1) * 16384;

        // V pair-load: 8 b64 reads for slice-pair np (dst statically indexed)
        auto loadVpair = [&](int np, u32x2* dst) {
#pragma unroll
            for (int nn = 0; nn < 4; ++nn) {
                s16x4 v0 = *(const s16x4*)(Vc + (nn * 16 + lr) * 256 +
                                           (((4 * np + (lg >> 1)) ^ (lr & 7)) << 4) +
                                           ((lg & 1) << 3));
                s16x4 v1 = *(const s16x4*)(Vc + (nn * 16 + lr) * 256 +
                                           (((4 * np + 2 + (lg >> 1)) ^ (lr & 7)) << 4) +
                                           ((lg & 1) << 3));
                dst[2 * nn] = __builtin_bit_cast(u32x2, v0);
                dst[2 * nn + 1] = __builtin_bit_cast(u32x2, v1);
            }
        };

        f32x4 saA[8], saB[8];
        __builtin_amdgcn_s_setprio(1);
#pragma unroll
        for (int n = 0; n < 8; ++n) {
            bf16x8 kf = *(const bf16x8*)(Kc + (n * 16 + lr) * 128 +
                                         ((lg ^ (lr & 7)) << 4));
            saA[n] = __builtin_amdgcn_mfma_f32_16x16x32_bf16(kf, qa0A, abF2[n],
                                                             0, 0, 0);
            saB[n] = __builtin_amdgcn_mfma_f32_16x16x32_bf16(kf, qa0B, abF2[n],
                                                             0, 0, 0);
        }
#pragma unroll
        for (int n = 0; n < 8; ++n) {
            bf16x8 kf = *(const bf16x8*)(Kc + (n * 16 + lr) * 128 +
                                         (((4 + lg) ^ (lr & 7)) << 4));
            saA[n] = __builtin_amdgcn_mfma_f32_16x16x32_bf16(kf, qa1A, saA[n],
                                                             0, 0, 0);
            saB[n] = __builtin_amdgcn_mfma_f32_16x16x32_bf16(kf, qa1B, saB[n],
                                                             0, 0, 0);
        }
        __builtin_amdgcn_s_setprio(0);

        // prefetch pair 0 (latency hides under the exp chain)
        u32x2 vP[8], vQ[8];
        loadVpair(0, vP);

        // max-free softmax: P = exp2(sa)
#pragma unroll
        for (int n = 0; n < 8; ++n)
#pragma unroll
            for (int r = 0; r < 4; ++r) {
                saA[n][r] = fexp2(saA[n][r]);
                saB[n][r] = fexp2(saB[n][r]);
            }
#pragma unroll
        for (int n = 0; n < 8; ++n) abF2[n] += ainc;

        // pack all 8 slices to bf16 pairs
        u32 pA[8][2], pB[8][2];
#pragma unroll
        for (int n = 0; n < 8; ++n) {
            asm("v_cvt_pk_bf16_f32 %0, %1, %2"
                : "=v"(pA[n][0]) : "v"(saA[n][0]), "v"(saA[n][1]));
            asm("v_cvt_pk_bf16_f32 %0, %1, %2"
                : "=v"(pA[n][1]) : "v"(saA[n][2]), "v"(saA[n][3]));
            asm("v_cvt_pk_bf16_f32 %0, %1, %2"
                : "=v"(pB[n][0]) : "v"(saB[n][0]), "v"(saB[n][1]));
            asm("v_cvt_pk_bf16_f32 %0, %1, %2"
                : "=v"(pB[n][1]) : "v"(saB[n][2]), "v"(saB[n][3]));
        }

        // PV + l per 32-j slice-pair: K=32 MFMA, concatenated frags.
        auto pvPair = [&](int np, const u32x2* va) {
            const int n0 = 2 * np, n1 = 2 * np + 1;
            u32x4 bwA = {pA[n0][0], pA[n0][1], pA[n1][0], pA[n1][1]};
            u32x4 bwB = {pB[n0][0], pB[n0][1], pB[n1][0], pB[n1][1]};
            bf16x8 pfA = __builtin_bit_cast(bf16x8, bwA);
            bf16x8 pfB = __builtin_bit_cast(bf16x8, bwB);
            laccA = __builtin_amdgcn_mfma_f32_16x16x32_bf16(onesf, pfA,
                                                            laccA, 0, 0, 0);
            laccB = __builtin_amdgcn_mfma_f32_16x16x32_bf16(onesf, pfB,
                                                            laccB, 0, 0, 0);
#pragma unroll
            for (int nn = 0; nn < 4; ++nn) {
                u32x4 aw = {va[2 * nn][0], va[2 * nn][1],
                            va[2 * nn + 1][0], va[2 * nn + 1][1]};
                bf16x8 vaf = __builtin_bit_cast(bf16x8, aw);
                oaccA[nn] = __builtin_amdgcn_mfma_f32_16x16x32_bf16(vaf, pfA,
                                                                    oaccA[nn],
                                                                    0, 0, 0);
                oaccB[nn] = __builtin_amdgcn_mfma_f32_16x16x32_bf16(vaf, pfB,
                                                                    oaccB[nn],
                                                                    0, 0, 0);
            }
        };
        __builtin_amdgcn_s_setprio(1);
        loadVpair(1, vQ);
        pvPair(0, vP);
        loadVpair(2, vP);
        pvPair(1, vQ);
        loadVpair(3, vQ);
        pvPair(2, vP);
        pvPair(3, vQ);
        __builtin_amdgcn_s_setprio(0);

        asm volatile("s_waitcnt vmcnt(0)" ::: "memory");
        __builtin_amdgcn_s_barrier();
        __builtin_amdgcn_sched_barrier(0);
    }

    const float linvA = 1.0f / laccA[0];
    const float linvB = 1.0f / laccB[0];
    u16* ow = smem + w * (32 * 72);
#pragma unroll
    for (int nn = 0; nn < 4; ++nn)
#pragma unroll
        for (int r = 0; r < 4; ++r) {
            ow[lr * 72 + nn * 16 + 4 * lg + r] = f2bf(oaccA[nn][r] * linvA);
            ow[(16 + lr) * 72 + nn * 16 + 4 * lg + r] = f2bf(oaccB[nn][r] * linvB);
        }
    __syncthreads();
    const int q_ = lane >> 2, d0 = (lane & 3) << 4;
    const u16* orowA = smem + w * (32 * 72) + q_ * 72 + d0;
    const u16* orowB = orowA + 16 * 72;
    u16x8 a0 = *(const u16x8*)(orowA);
    u16x8 a1 = *(const u16x8*)(orowA + 8);
    u16x8 b0 = *(const u16x8*)(orowB);
    u16x8 b1 = *(const u16x8*)(orowB + 8);
    size_t gaddr = ((size_t)bb * 2048 + q0 + w * 32 + q_) * 1024 + h * 64 + d0;
    *(u16x8*)(ao + gaddr) = a0;
    *(u16x8*)(ao + gaddr + 8) = a1;
    *(u16x8*)(ao + gaddr + 16 * 1024) = b0;
    *(u16x8*)(ao + gaddr + 16 * 1024 + 8) = b1;
}

// ---------------------------------------------------------------- launch
extern "C" void kernel_launch(void* const* d_in, const int* in_sizes, int n_in,
                              void* d_out, int out_size, void* d_ws, size_t ws_size,
                              hipStream_t stream) {
    const float* x  = (const float*)d_in[0];
    const float* Wq = (const float*)d_in[1];
    const float* bq = (const float*)d_in[2];
    const float* Wk = (const float*)d_in[3];
    const float* bk = (const float*)d_in[4];
    const float* Wv = (const float*)d_in[5];
    const float* bv = (const float*)d_in[6];
    const float* Wo = (const float*)d_in[7];
    const float* bo = (const float*)d_in[8];

    const size_t MB = 1u << 20;
    if (ws_size < 40 * MB) return;
    char* ws = (char*)d_ws;
    u16* xb    = (u16*)(ws);             // 8MB  [4096][1024] bf16 (reused as ao)
    u16* wqkvt = (u16*)(ws + 8 * MB);    // 6MB  [3072][1024] = [Wq^T;Wk^T;Wv^T]
    u16* wot   = (u16*)(ws + 14 * MB);   // 2MB  Wo^T
    u16* qb    = (u16*)(ws + 16 * MB);   // 8MB  [32][2048][64]
    u16* kb    = (u16*)(ws + 24 * MB);   // 8MB  [32][2048][64]
    u16* vt    = (u16*)(ws + 32 * MB);   // 8MB  [32][64][2048]
    u16* ao    = xb;

    cvt_all_k<<<dim3(16, 16, 12), 256, 0, stream>>>(Wq, Wk, Wv, Wo, x,
                                                    wqkvt, wot, xb);

    gemm_k<0><<<dim3(32, 24), 256, 0, stream>>>(xb, wqkvt, bq, bk, bv,
                                                qb, kb, vt, nullptr);
    attn_k<<<dim3(16, 32), 256, 0, stream>>>(qb, kb, vt, ao);
    gemm_k<1><<<dim3(32, 8), 256, 0, stream>>>(ao, wot, bo, nullptr, nullptr,
                                               nullptr, nullptr, nullptr,
                                               (float*)d_out);
}

// Round 22
// 107.455 us; speedup vs baseline: 1.1113x; 1.1113x over previous
//
#include <hip/hip_runtime.h>
#include <cstdint>
#include <cstddef>

typedef unsigned short u16;
typedef unsigned int u32;
typedef __bf16 bf16x8 __attribute__((ext_vector_type(8)));
typedef float f32x4 __attribute__((ext_vector_type(4)));
typedef u32 u32x2 __attribute__((ext_vector_type(2)));
typedef u32 u32x4 __attribute__((ext_vector_type(4)));
typedef unsigned short u16x8 __attribute__((ext_vector_type(8)));
typedef short s16x4 __attribute__((ext_vector_type(4)));

// f32 -> bf16 round-to-nearest-even (finite inputs only)
__device__ __forceinline__ u16 f2bf(float f) {
    u32 u = __float_as_uint(f);
    u += 0x7fffu + ((u >> 16) & 1u);
    return (u16)(u >> 16);
}

// raw exp2: single v_exp_f32 (denormals flush to 0 = correct softmax tail)
__device__ __forceinline__ float fexp2(float x) {
    float r;
    asm("v_exp_f32 %0, %1" : "=v"(r) : "v"(x));
    return r;
}

// async global->LDS, 16B per lane. LDS ptr must be wave-uniform; HW adds lane*16.
__device__ __forceinline__ void gl16(const void* g, void* l) {
    __builtin_amdgcn_global_load_lds(
        (const __attribute__((address_space(1))) unsigned int*)g,
        (__attribute__((address_space(3))) unsigned int*)l, 16, 0, 0);
}

// ---------------------------------------------------------------- conversions
// z 0..3: W [1024][1024] f32 (k,n) -> bf16 (n,k). z 4..11: x f32 -> bf16 chunks.
__global__ __launch_bounds__(256) void cvt_all_k(const float* __restrict__ Wq,
                                                 const float* __restrict__ Wk,
                                                 const float* __restrict__ Wv,
                                                 const float* __restrict__ Wo,
                                                 const float* __restrict__ x,
                                                 u16* __restrict__ oqkv,
                                                 u16* __restrict__ oo,
                                                 u16* __restrict__ ox) {
    const int z = blockIdx.z;
    const int bx = blockIdx.x, by = blockIdx.y;
    const int t = threadIdx.x;
    if (z >= 4) {   // x conversion: 8 f32 per thread
        int i = ((z - 4) * 256 + by * 16 + bx) * 256 + t;
        const float4* xv = (const float4*)x;
        float4 a = xv[2 * i], b = xv[2 * i + 1];
        ushort4 r0, r1;
        r0.x = f2bf(a.x); r0.y = f2bf(a.y); r0.z = f2bf(a.z); r0.w = f2bf(a.w);
        r1.x = f2bf(b.x); r1.y = f2bf(b.y); r1.z = f2bf(b.z); r1.w = f2bf(b.w);
        ((ushort4*)ox)[2 * i] = r0;
        ((ushort4*)ox)[2 * i + 1] = r1;
        return;
    }
    __shared__ float tile[64][65];
    const float* W = (z == 0) ? Wq : (z == 1) ? Wk : (z == 2) ? Wv : Wo;
    u16* o = (z < 3) ? (oqkv + ((size_t)z << 20)) : oo;
    const int tn = t & 63, tr = t >> 6;
#pragma unroll
    for (int r = 0; r < 16; ++r) {
        int kk = r * 4 + tr;
        tile[kk][tn] = W[(size_t)(by * 64 + kk) * 1024 + bx * 64 + tn];
    }
    __syncthreads();
#pragma unroll
    for (int r = 0; r < 16; ++r) {
        int nn = r * 4 + tr;
        o[(size_t)(bx * 64 + nn) * 1024 + by * 64 + tn] = f2bf(tile[tn][nn]);
    }
}

// ---------------------------------------------------------------- GEMM 128x128
// 3-buffer depth-2 counted-vmcnt pipeline; zero-conflict both-sides swizzle.
// MODE 0: fused QKV epilogue; V-blocks store via LDS transpose (coalesced).
// MODE 1: f32 out + bias.
// (R21's 2-buffer/32KB variant regressed: the hoped-for 3rd co-resident block
// never materialized; depth-2 counted vmcnt is the proven config.)
template <int MODE>
__global__ __launch_bounds__(256) void gemm_k(
    const u16* __restrict__ A, const u16* __restrict__ Bt,
    const float* __restrict__ bias0, const float* __restrict__ bias1,
    const float* __restrict__ bias2,
    u16* __restrict__ oq, u16* __restrict__ ok_, u16* __restrict__ ov,
    float* __restrict__ oc) {
    __shared__ __align__(16) u16 sh[2 * 3 * 128 * 32];   // 48KB total
    u16* As = sh;
    u16* Bs = sh + 3 * 128 * 32;
    const int t = threadIdx.x, w = t >> 6, lane = t & 63;
    const int lr = lane & 15, lg = lane >> 4;
    const int brow = blockIdx.x * 128, bcol = blockIdx.y * 128;
    const int wr = w >> 1, wc = w & 1;
    const char* Ab = (const char*)A + (size_t)brow * 2048;
    const char* Bb = (const char*)Bt + (size_t)bcol * 2048;
    const int lrow = lane >> 2;
    const int lcol = (((lane & 3) ^ ((lane >> 3) & 3)) << 4);
    const int r0a = w * 32, r0b = w * 32 + 16;
    const size_t ga = (size_t)(r0a + lrow) * 2048 + lcol;
    const size_t gb = (size_t)(r0b + lrow) * 2048 + lcol;
    const int rsw = ((lg ^ ((lr >> 1) & 3)) << 4);

    f32x4 acc[4][4];
#pragma unroll
    for (int m = 0; m < 4; ++m)
#pragma unroll
        for (int n = 0; n < 4; ++n) acc[m][n] = (f32x4){0.f, 0.f, 0.f, 0.f};

    gl16(Ab + ga, (char*)As + r0a * 64);
    gl16(Ab + gb, (char*)As + r0b * 64);
    gl16(Bb + ga, (char*)Bs + r0a * 64);
    gl16(Bb + gb, (char*)Bs + r0b * 64);
    gl16(Ab + ga + 64, (char*)As + 8192 + r0a * 64);
    gl16(Ab + gb + 64, (char*)As + 8192 + r0b * 64);
    gl16(Bb + ga + 64, (char*)Bs + 8192 + r0a * 64);
    gl16(Bb + gb + 64, (char*)Bs + 8192 + r0b * 64);

    for (int tt = 0; tt < 32; ++tt) {
        if (tt < 31) {
            asm volatile("s_waitcnt vmcnt(4)" ::: "memory");
        } else {
            asm volatile("s_waitcnt vmcnt(0)" ::: "memory");
        }
        __builtin_amdgcn_s_barrier();
        __builtin_amdgcn_sched_barrier(0);
        if (tt < 30) {
            const int nb = (tt + 2) % 3;
            const size_t ko = (size_t)(tt + 2) * 64;
            char* Asn = (char*)As + nb * 8192;
            char* Bsn = (char*)Bs + nb * 8192;
            gl16(Ab + ga + ko, Asn + r0a * 64);
            gl16(Ab + gb + ko, Asn + r0b * 64);
            gl16(Bb + ga + ko, Bsn + r0a * 64);
            gl16(Bb + gb + ko, Bsn + r0b * 64);
        }
        const char* AsB = (const char*)As + (tt % 3) * 8192;
        const char* BsB = (const char*)Bs + (tt % 3) * 8192;
        bf16x8 af[4], bfr[4];
#pragma unroll
        for (int m = 0; m < 4; ++m)
            af[m] = *(const bf16x8*)(AsB + (wr * 64 + m * 16 + lr) * 64 + rsw);
#pragma unroll
        for (int n = 0; n < 4; ++n)
            bfr[n] = *(const bf16x8*)(BsB + (wc * 64 + n * 16 + lr) * 64 + rsw);
#pragma unroll
        for (int m = 0; m < 4; ++m)
#pragma unroll
            for (int n = 0; n < 4; ++n)
                acc[m][n] = __builtin_amdgcn_mfma_f32_16x16x32_bf16(af[m], bfr[n],
                                                                    acc[m][n], 0, 0, 0);
    }

    const float QSCALE = 0.125f * 1.44269504f;
    if (MODE == 0 && bcol >= 2048) {
        // V block: transpose via LDS, store coalesced 128B runs into vt.
        const int b = brow >> 11, l0 = brow & 2047;
        __syncthreads();
#pragma unroll
        for (int n = 0; n < 4; ++n) {
            const int cl = wc * 64 + n * 16 + lr;
            const float bb2 = bias2[bcol - 2048 + cl];
#pragma unroll
            for (int m = 0; m < 4; ++m)
#pragma unroll
                for (int r = 0; r < 4; ++r) {
                    int ll = wr * 64 + m * 16 + 4 * lg + r;
                    sh[cl * 136 + ll] = f2bf(acc[m][n][r] + bb2);
                }
        }
        __syncthreads();
        const int rr = t >> 1, hf = t & 1;
        const u16* src = sh + rr * 136 + hf * 64;
        u16* dst = ov + ((size_t)b * 1024 + (bcol - 2048) + rr) * 2048 +
                   l0 + hf * 64;
#pragma unroll
        for (int i = 0; i < 8; ++i)
            *(u16x8*)(dst + i * 8) = *(const u16x8*)(src + i * 8);
        return;
    }
#pragma unroll
    for (int n = 0; n < 4; ++n) {
        const int col = bcol + wc * 64 + n * 16 + lr;
        if (MODE == 0) {
#pragma unroll
            for (int m = 0; m < 4; ++m)
#pragma unroll
                for (int r = 0; r < 4; ++r) {
                    int row = brow + wr * 64 + m * 16 + 4 * lg + r;
                    int b = row >> 11, l = row & 2047;
                    float val = acc[m][n][r];
                    if (col < 1024) {
                        int hh = col >> 6, d = col & 63;
                        oq[(((size_t)b * 16 + hh) * 2048 + l) * 64 + d] =
                            f2bf((val + bias0[col]) * QSCALE);
                    } else {
                        int c = col - 1024, hh = c >> 6, d = c & 63;
                        ok_[(((size_t)b * 16 + hh) * 2048 + l) * 64 + d] =
                            f2bf(val + bias1[c]);
                    }
                }
        } else {
            const float bb = bias0[col];
#pragma unroll
            for (int m = 0; m < 4; ++m)
#pragma unroll
                for (int r = 0; r < 4; ++r) {
                    int row = brow + wr * 64 + m * 16 + 4 * lg + r;
                    oc[(size_t)row * 1024 + col] = acc[m][n][r] + bb;
                }
        }
    }
}

// ---------------------------------------------------------------- attention
// (R18 version: KVBLK=128, 2-buffer depth-1, 32-row waves, max-free softmax
// in MFMA C-init, K=32 PV concatenated slice pairs, 1-deep vP/vQ V-register
// prefetch, v_exp_f32.)
__global__ __launch_bounds__(256, 2) void attn_k(const u16* __restrict__ qg_,
                                                 const u16* __restrict__ kg_,
                                                 const u16* __restrict__ vg_,
                                                 u16* __restrict__ ao) {
    __shared__ __align__(16) u16 smem[32768];   // 64KB: K0|K1 | V0|V1 (16KB ea)
    char* Kbase = (char*)smem;                  // 2 x 16384
    char* Vbase = (char*)smem + 32768;          // 2 x 16384
    const int t = threadIdx.x, w = t >> 6, lane = t & 63;
    const int lr = lane & 15, lg = lane >> 4;
    const int bid = blockIdx.y * 16 + blockIdx.x;
    const int qt = (bid >> 3) & 15;
    const int bh = ((bid >> 7) << 3) | (bid & 7);
    const int q0 = qt * 128, h = bh & 15, bb = bh >> 4;
    const float sl2 = exp2f(-0.5f * (float)(h + 1)) * 1.44269504f; // slope*log2e

    const char* khead = (const char*)(kg_ + (size_t)bh * 2048 * 64);
    const char* vhead = (const char*)(vg_ + (size_t)bh * 64 * 2048);

    const int krow = lane >> 3, ku = lane & 7;
    const int kso = (w * 32 + krow) * 128 + ((ku ^ (krow & 7)) << 4);
    const int kdo = w * 4096;
    const int vrow = lane >> 4, vgr = lane & 15;
    int vso[4];
#pragma unroll
    for (int i = 0; i < 4; ++i)
        vso[i] = (w * 16 + 4 * i + vrow) * 4096 +
                 ((vgr ^ ((4 * i + vrow) & 7)) << 4);
    const int vdo = w * 4096;

    const char* qpA = (const char*)qg_ +
                      ((size_t)bh * 2048 + q0 + w * 32 + lr) * 128;
    bf16x8 qa0A = *(const bf16x8*)(qpA + lg * 16);
    bf16x8 qa1A = *(const bf16x8*)(qpA + 64 + lg * 16);
    bf16x8 qa0B = *(const bf16x8*)(qpA + 2048 + lg * 16);
    bf16x8 qa1B = *(const bf16x8*)(qpA + 2048 + 64 + lg * 16);

    f32x4 abF2[8];
#pragma unroll
    for (int n = 0; n < 8; ++n)
#pragma unroll
        for (int r = 0; r < 4; ++r)
            abF2[n][r] = sl2 * (float)(n * 16 + 4 * lg + r - 2047) - 16.0f;
    const float ainc = sl2 * 128.0f;
    f32x4 oaccA[4], oaccB[4];
#pragma unroll
    for (int nn = 0; nn < 4; ++nn) {
        oaccA[nn] = (f32x4){0.f, 0.f, 0.f, 0.f};
        oaccB[nn] = (f32x4){0.f, 0.f, 0.f, 0.f};
    }
    f32x4 laccA = (f32x4){0.f, 0.f, 0.f, 0.f};
    f32x4 laccB = (f32x4){0.f, 0.f, 0.f, 0.f};
    const u32x4 ones32 = {0x3F803F80u, 0x3F803F80u, 0x3F803F80u, 0x3F803F80u};
    const bf16x8 onesf = __builtin_bit_cast(bf16x8, ones32);

    {
        char* kd = Kbase + kdo;
        char* vd = Vbase + vdo;
#pragma unroll
        for (int i = 0; i < 4; ++i) gl16(khead + kso + i * 1024, kd + i * 1024);
#pragma unroll
        for (int i = 0; i < 4; ++i) gl16(vhead + vso[i], vd + i * 1024);
    }
    asm volatile("s_waitcnt vmcnt(0)" ::: "memory");
    __builtin_amdgcn_s_barrier();
    __builtin_amdgcn_sched_barrier(0);

    for (int tt = 0; tt < 16; ++tt) {
        if (tt < 15) {
            const char* ks = khead + (size_t)(tt + 1) * 16384;
            const char* vs = vhead + (size_t)(tt + 1) * 256;
            char* kd = Kbase + ((tt + 1) & 1) * 16384 + kdo;
            char* vd = Vbase + ((tt + 1) & 1) * 16384 + vdo;
#pragma unroll
            for (int i = 0; i < 4; ++i) gl16(ks + kso + i * 1024, kd + i * 1024);
#pragma unroll
            for (int i = 0; i < 4; ++i) gl16(vs + vso[i], vd + i * 1024);
        }
        const char* Kc = Kbase + (tt & 1) * 16384;
        const char* Vc = Vbase + (tt & 1) * 16384;

        // V pair-load: 8 b64 reads for slice-pair np (dst statically indexed)
        auto loadVpair = [&](int np, u32x2* dst) {
#pragma unroll
            for (int nn = 0; nn < 4; ++nn) {
                s16x4 v0 = *(const s16x4*)(Vc + (nn * 16 + lr) * 256 +
                                           (((4 * np + (lg >> 1)) ^ (lr & 7)) << 4) +
                                           ((lg & 1) << 3));
                s16x4 v1 = *(const s16x4*)(Vc + (nn * 16 + lr) * 256 +
                                           (((4 * np + 2 + (lg >> 1)) ^ (lr & 7)) << 4) +
                                           ((lg & 1) << 3));
                dst[2 * nn] = __builtin_bit_cast(u32x2, v0);
                dst[2 * nn + 1] = __builtin_bit_cast(u32x2, v1);
            }
        };

        f32x4 saA[8], saB[8];
        __builtin_amdgcn_s_setprio(1);
#pragma unroll
        for (int n = 0; n < 8; ++n) {
            bf16x8 kf = *(const bf16x8*)(Kc + (n * 16 + lr) * 128 +
                                         ((lg ^ (lr & 7)) << 4));
            saA[n] = __builtin_amdgcn_mfma_f32_16x16x32_bf16(kf, qa0A, abF2[n],
                                                             0, 0, 0);
            saB[n] = __builtin_amdgcn_mfma_f32_16x16x32_bf16(kf, qa0B, abF2[n],
                                                             0, 0, 0);
        }
#pragma unroll
        for (int n = 0; n < 8; ++n) {
            bf16x8 kf = *(const bf16x8*)(Kc + (n * 16 + lr) * 128 +
                                         (((4 + lg) ^ (lr & 7)) << 4));
            saA[n] = __builtin_amdgcn_mfma_f32_16x16x32_bf16(kf, qa1A, saA[n],
                                                             0, 0, 0);
            saB[n] = __builtin_amdgcn_mfma_f32_16x16x32_bf16(kf, qa1B, saB[n],
                                                             0, 0, 0);
        }
        __builtin_amdgcn_s_setprio(0);

        // prefetch pair 0 (latency hides under the exp chain)
        u32x2 vP[8], vQ[8];
        loadVpair(0, vP);

        // max-free softmax: P = exp2(sa)
#pragma unroll
        for (int n = 0; n < 8; ++n)
#pragma unroll
            for (int r = 0; r < 4; ++r) {
                saA[n][r] = fexp2(saA[n][r]);
                saB[n][r] = fexp2(saB[n][r]);
            }
#pragma unroll
        for (int n = 0; n < 8; ++n) abF2[n] += ainc;

        // pack all 8 slices to bf16 pairs
        u32 pA[8][2], pB[8][2];
#pragma unroll
        for (int n = 0; n < 8; ++n) {
            asm("v_cvt_pk_bf16_f32 %0, %1, %2"
                : "=v"(pA[n][0]) : "v"(saA[n][0]), "v"(saA[n][1]));
            asm("v_cvt_pk_bf16_f32 %0, %1, %2"
                : "=v"(pA[n][1]) : "v"(saA[n][2]), "v"(saA[n][3]));
            asm("v_cvt_pk_bf16_f32 %0, %1, %2"
                : "=v"(pB[n][0]) : "v"(saB[n][0]), "v"(saB[n][1]));
            asm("v_cvt_pk_bf16_f32 %0, %1, %2"
                : "=v"(pB[n][1]) : "v"(saB[n][2]), "v"(saB[n][3]));
        }

        // PV + l per 32-j slice-pair: K=32 MFMA, concatenated frags.
        auto pvPair = [&](int np, const u32x2* va) {
            const int n0 = 2 * np, n1 = 2 * np + 1;
            u32x4 bwA = {pA[n0][0], pA[n0][1], pA[n1][0], pA[n1][1]};
            u32x4 bwB = {pB[n0][0], pB[n0][1], pB[n1][0], pB[n1][1]};
            bf16x8 pfA = __builtin_bit_cast(bf16x8, bwA);
            bf16x8 pfB = __builtin_bit_cast(bf16x8, bwB);
            laccA = __builtin_amdgcn_mfma_f32_16x16x32_bf16(onesf, pfA,
                                                            laccA, 0, 0, 0);
            laccB = __builtin_amdgcn_mfma_f32_16x16x32_bf16(onesf, pfB,
                                                            laccB, 0, 0, 0);
#pragma unroll
            for (int nn = 0; nn < 4; ++nn) {
                u32x4 aw = {va[2 * nn][0], va[2 * nn][1],
                            va[2 * nn + 1][0], va[2 * nn + 1][1]};
                bf16x8 vaf = __builtin_bit_cast(bf16x8, aw);
                oaccA[nn] = __builtin_amdgcn_mfma_f32_16x16x32_bf16(vaf, pfA,
                                                                    oaccA[nn],
                                                                    0, 0, 0);
                oaccB[nn] = __builtin_amdgcn_mfma_f32_16x16x32_bf16(vaf, pfB,
                                                                    oaccB[nn],
                                                                    0, 0, 0);
            }
        };
        __builtin_amdgcn_s_setprio(1);
        loadVpair(1, vQ);
        pvPair(0, vP);
        loadVpair(2, vP);
        pvPair(1, vQ);
        loadVpair(3, vQ);
        pvPair(2, vP);
        pvPair(3, vQ);
        __builtin_amdgcn_s_setprio(0);

        asm volatile("s_waitcnt vmcnt(0)" ::: "memory");
        __builtin_amdgcn_s_barrier();
        __builtin_amdgcn_sched_barrier(0);
    }

    const float linvA = 1.0f / laccA[0];
    const float linvB = 1.0f / laccB[0];
    u16* ow = smem + w * (32 * 72);
#pragma unroll
    for (int nn = 0; nn < 4; ++nn)
#pragma unroll
        for (int r = 0; r < 4; ++r) {
            ow[lr * 72 + nn * 16 + 4 * lg + r] = f2bf(oaccA[nn][r] * linvA);
            ow[(16 + lr) * 72 + nn * 16 + 4 * lg + r] = f2bf(oaccB[nn][r] * linvB);
        }
    __syncthreads();
    const int q_ = lane >> 2, d0 = (lane & 3) << 4;
    const u16* orowA = smem + w * (32 * 72) + q_ * 72 + d0;
    const u16* orowB = orowA + 16 * 72;
    u16x8 a0 = *(const u16x8*)(orowA);
    u16x8 a1 = *(const u16x8*)(orowA + 8);
    u16x8 b0 = *(const u16x8*)(orowB);
    u16x8 b1 = *(const u16x8*)(orowB + 8);
    size_t gaddr = ((size_t)bb * 2048 + q0 + w * 32 + q_) * 1024 + h * 64 + d0;
    *(u16x8*)(ao + gaddr) = a0;
    *(u16x8*)(ao + gaddr + 8) = a1;
    *(u16x8*)(ao + gaddr + 16 * 1024) = b0;
    *(u16x8*)(ao + gaddr + 16 * 1024 + 8) = b1;
}

// ---------------------------------------------------------------- launch
extern "C" void kernel_launch(void* const* d_in, const int* in_sizes, int n_in,
                              void* d_out, int out_size, void* d_ws, size_t ws_size,
                              hipStream_t stream) {
    const float* x  = (const float*)d_in[0];
    const float* Wq = (const float*)d_in[1];
    const float* bq = (const float*)d_in[2];
    const float* Wk = (const float*)d_in[3];
    const float* bk = (const float*)d_in[4];
    const float* Wv = (const float*)d_in[5];
    const float* bv = (const float*)d_in[6];
    const float* Wo = (const float*)d_in[7];
    const float* bo = (const float*)d_in[8];

    const size_t MB = 1u << 20;
    if (ws_size < 40 * MB) return;
    char* ws = (char*)d_ws;
    u16* xb    = (u16*)(ws);             // 8MB  [4096][1024] bf16 (reused as ao)
    u16* wqkvt = (u16*)(ws + 8 * MB);    // 6MB  [3072][1024] = [Wq^T;Wk^T;Wv^T]
    u16* wot   = (u16*)(ws + 14 * MB);   // 2MB  Wo^T
    u16* qb    = (u16*)(ws + 16 * MB);   // 8MB  [32][2048][64]
    u16* kb    = (u16*)(ws + 24 * MB);   // 8MB  [32][2048][64]
    u16* vt    = (u16*)(ws + 32 * MB);   // 8MB  [32][64][2048]
    u16* ao    = xb;

    cvt_all_k<<<dim3(16, 16, 12), 256, 0, stream>>>(Wq, Wk, Wv, Wo, x,
                                                    wqkvt, wot, xb);

    gemm_k<0><<<dim3(32, 24), 256, 0, stream>>>(xb, wqkvt, bq, bk, bv,
                                                qb, kb, vt, nullptr);
    attn_k<<<dim3(16, 32), 256, 0, stream>>>(qb, kb, vt, ao);
    gemm_k<1><<<dim3(32, 8), 256, 0, stream>>>(ao, wot, bo, nullptr, nullptr,
                                               nullptr, nullptr, nullptr,
                                               (float*)d_out);
}